// Round 1
// baseline (390.505 us; speedup 1.0000x reference)
//
#include <hip/hip_runtime.h>
#include <hip/hip_bf16.h>
#include <math.h>

#define B 8
#define N 2048
#define C 16
#define HID 128
#define NRF 16384      // 128*128
#define MAXLEN 8
#define MAXCH 2048     // max chains per batch (<= N)

// ---------------- init: zero per-rf counters, map=-1, cnt=0 ----------------
__global__ void k_init(int* __restrict__ cntrf, int* __restrict__ map,
                       int* __restrict__ cnt) {
    int i = blockIdx.x * blockDim.x + threadIdx.x;   // 0 .. B*NRF
    if (i < B * NRF) { cntrf[i] = 0; map[i] = -1; }
    if (i < B) cnt[i] = 0;
}

// ---------------- prep: transpose weights, sum biases ----------------
__global__ void k_prep(const float* __restrict__ w_ih, const float* __restrict__ w_hh,
                       const float* __restrict__ b_ih, const float* __restrict__ b_hh,
                       float* __restrict__ w_ih_T, float* __restrict__ w_hh_T,
                       float* __restrict__ biassum) {
    int idx = blockIdx.x * blockDim.x + threadIdx.x;
    if (idx < C * 512) {                       // w_ih_T[c][j] = w_ih[j][c]
        int c = idx >> 9, j = idx & 511;
        w_ih_T[idx] = w_ih[j * C + c];
    } else if (idx < C * 512 + HID * 512) {    // w_hh_T[k][j] = w_hh[j][k]
        int t = idx - C * 512;
        int k = t >> 9, j = t & 511;
        w_hh_T[t] = w_hh[j * HID + k];
    } else if (idx < C * 512 + HID * 512 + 512) {
        int j = idx - (C * 512 + HID * 512);
        biassum[j] = b_ih[j] + b_hh[j];
    }
}

// ---------------- build: bucket events by (b, rf) ----------------
__global__ void k_build(const int* __restrict__ coords, int* __restrict__ cntrf,
                        int* __restrict__ map, int* __restrict__ cnt,
                        int* __restrict__ chainrf, int* __restrict__ slots) {
    int idx = blockIdx.x * blockDim.x + threadIdx.x;   // 0 .. B*N
    if (idx >= B * N) return;
    int b = idx >> 11;              // /N
    int n = idx & (N - 1);
    int x = coords[idx * 2 + 0];
    int y = coords[idx * 2 + 1];
    int rf = y * 128 + x;
    int pos = atomicAdd(&cntrf[b * NRF + rf], 1);
    if (pos < MAXLEN) slots[(b * NRF + rf) * MAXLEN + pos] = n;
    if (pos == 0) {                 // register chain
        int k = atomicAdd(&cnt[b], 1);
        chainrf[b * MAXCH + k] = rf;
        map[b * NRF + rf] = k;
    }
}

// ---------------- lstm over chains: one wave per chain ----------------
__global__ __launch_bounds__(64) void k_lstm(
    const float* __restrict__ features, const float* __restrict__ w_ih_T,
    const float* __restrict__ w_hh_T, const float* __restrict__ biassum,
    const int* __restrict__ cnt, const int* __restrict__ chainrf,
    const int* __restrict__ cntrf, const int* __restrict__ slots,
    float* __restrict__ hfin) {
    int b = blockIdx.x >> 9;        // grid = B * 512 blocks
    int j0 = blockIdx.x & 511;
    int lane = threadIdx.x;
    __shared__ float lds_h[HID];
    __shared__ float lds_x[C];
    int nch = cnt[b];
    for (int j = j0; j < nch; j += 512) {
        int rf = chainrf[b * MAXCH + j];
        int len = cntrf[b * NRF + rf];
        if (len > MAXLEN) len = MAXLEN;
        int ev[MAXLEN];
#pragma unroll
        for (int t = 0; t < MAXLEN; t++) ev[t] = 0x7fffffff;
        for (int t = 0; t < len; t++) ev[t] = slots[(b * NRF + rf) * MAXLEN + t];
        // sort ascending (time order); bubble over fixed 8, branch-free
#pragma unroll
        for (int a = 0; a < MAXLEN; a++)
#pragma unroll
            for (int q = 0; q < MAXLEN - 1; q++) {
                int u = ev[q], v = ev[q + 1];
                ev[q] = min(u, v);
                ev[q + 1] = max(u, v);
            }
        float c0 = 0.f, c1 = 0.f, h0 = 0.f, h1 = 0.f;
        for (int t = 0; t < len; t++) {
            int n = ev[t];
            if (lane < C) lds_x[lane] = features[(b * N + n) * C + lane];
            __syncthreads();
            float acc[8];
#pragma unroll
            for (int r = 0; r < 8; r++) acc[r] = biassum[lane + 64 * r];
#pragma unroll
            for (int ci = 0; ci < C; ci++) {
                float xv = lds_x[ci];
#pragma unroll
                for (int r = 0; r < 8; r++)
                    acc[r] += w_ih_T[ci * 512 + lane + 64 * r] * xv;
            }
            if (t > 0) {
                for (int k = 0; k < HID; k++) {
                    float hv = lds_h[k];
#pragma unroll
                    for (int r = 0; r < 8; r++)
                        acc[r] += w_hh_T[k * 512 + lane + 64 * r] * hv;
                }
            }
            // gate order (torch): i,f,g,o ; lane owns hid=lane (r even) and hid=lane+64 (r odd)
            float i0 = 1.f / (1.f + expf(-acc[0]));
            float i1 = 1.f / (1.f + expf(-acc[1]));
            float f0 = 1.f / (1.f + expf(-acc[2]));
            float f1 = 1.f / (1.f + expf(-acc[3]));
            float g0 = tanhf(acc[4]);
            float g1 = tanhf(acc[5]);
            float o0 = 1.f / (1.f + expf(-acc[6]));
            float o1 = 1.f / (1.f + expf(-acc[7]));
            c0 = f0 * c0 + i0 * g0;
            c1 = f1 * c1 + i1 * g1;
            h0 = o0 * tanhf(c0);
            h1 = o1 * tanhf(c1);
            __syncthreads();
            lds_h[lane] = h0;
            lds_h[lane + 64] = h1;
            __syncthreads();
        }
        hfin[(b * MAXCH + j) * HID + lane] = h0;
        hfin[(b * MAXCH + j) * HID + lane + 64] = h1;
    }
}

// ---------------- scatter to dense [B, HID, 128, 128] ----------------
__global__ __launch_bounds__(256) void k_scatter(
    const float* __restrict__ hfin, const int* __restrict__ map,
    float* __restrict__ out) {
    int b = blockIdx.x >> 7;        // grid = B*128
    int y = blockIdx.x & 127;
    int t = threadIdx.x;
    int xq = t & 31;                // x quad: covers x = 4*xq .. 4*xq+3
    int hg = t >> 5;                // hid group 0..7 (16 hids each)
    const int4* mrow = (const int4*)(map + b * NRF + y * 128);
    int4 kk = mrow[xq];
    const float* hb = hfin + (size_t)b * MAXCH * HID;
#pragma unroll
    for (int hh = 0; hh < 16; hh++) {
        int hid = hg * 16 + hh;
        float4 v;
        v.x = (kk.x < 0) ? 0.f : hb[kk.x * HID + hid];
        v.y = (kk.y < 0) ? 0.f : hb[kk.y * HID + hid];
        v.z = (kk.z < 0) ? 0.f : hb[kk.z * HID + hid];
        v.w = (kk.w < 0) ? 0.f : hb[kk.w * HID + hid];
        *(float4*)(out + ((((size_t)b * HID + hid) * 128 + y) * 128) + xq * 4) = v;
    }
}

extern "C" void kernel_launch(void* const* d_in, const int* in_sizes, int n_in,
                              void* d_out, int out_size, void* d_ws, size_t ws_size,
                              hipStream_t stream) {
    const float* features = (const float*)d_in[0];   // [B,N,C] f32
    const int*   coords   = (const int*)d_in[1];     // [B,N,2] i32
    const float* w_ih     = (const float*)d_in[2];   // [512,16]
    const float* w_hh     = (const float*)d_in[3];   // [512,128]
    const float* b_ih     = (const float*)d_in[4];   // [512]
    const float* b_hh     = (const float*)d_in[5];   // [512]
    float* out = (float*)d_out;                      // [B,128,128,128]

    char* ws = (char*)d_ws;
    float* w_ih_T  = (float*)(ws + 0);               //  32768 B
    float* w_hh_T  = (float*)(ws + 32768);           // 262144 B
    float* biassum = (float*)(ws + 294912);          //   2048 B
    int*   cntrf   = (int*)(ws + 296960);            // 524288 B
    int*   map     = (int*)(ws + 821248);            // 524288 B
    int*   cnt     = (int*)(ws + 1345536);           //     64 B
    int*   chainrf = (int*)(ws + 1345600);           //  65536 B
    int*   slots   = (int*)(ws + 1411136);           // 4194304 B
    float* hfin    = (float*)(ws + 5605440);         // 8388608 B -> ~13.4 MB total

    k_init<<<dim3((B * NRF + 255) / 256), dim3(256), 0, stream>>>(cntrf, map, cnt);
    k_prep<<<dim3((C * 512 + HID * 512 + 512 + 255) / 256), dim3(256), 0, stream>>>(
        w_ih, w_hh, b_ih, b_hh, w_ih_T, w_hh_T, biassum);
    k_build<<<dim3((B * N + 255) / 256), dim3(256), 0, stream>>>(
        coords, cntrf, map, cnt, chainrf, slots);
    k_lstm<<<dim3(B * 512), dim3(64), 0, stream>>>(
        features, w_ih_T, w_hh_T, biassum, cnt, chainrf, cntrf, slots, hfin);
    k_scatter<<<dim3(B * 128), dim3(256), 0, stream>>>(hfin, map, out);
}

// Round 2
// 214.866 us; speedup vs baseline: 1.8174x; 1.8174x over previous
//
#include <hip/hip_runtime.h>
#include <hip/hip_bf16.h>
#include <math.h>

#define B 8
#define N 2048
#define C 16
#define HID 128
#define NRF 16384      // 128*128
#define MAXLEN 8
#define MAXCH 2048     // max chains per batch (<= N)

// ---------------- init: zero per-rf counters, map=-1, cnt=0 ----------------
__global__ void k_init(int* __restrict__ cntrf, int* __restrict__ map,
                       int* __restrict__ cnt) {
    int i = blockIdx.x * blockDim.x + threadIdx.x;   // 0 .. B*NRF
    if (i < B * NRF) { cntrf[i] = 0; map[i] = -1; }
    if (i < B) cnt[i] = 0;
}

// ---------------- prep: transpose weights, sum biases ----------------
__global__ void k_prep(const float* __restrict__ w_ih, const float* __restrict__ w_hh,
                       const float* __restrict__ b_ih, const float* __restrict__ b_hh,
                       float* __restrict__ w_ih_T, float* __restrict__ w_hh_T,
                       float* __restrict__ biassum) {
    int idx = blockIdx.x * blockDim.x + threadIdx.x;
    if (idx < C * 512) {                       // w_ih_T[c][j] = w_ih[j][c]
        int c = idx >> 9, j = idx & 511;
        w_ih_T[idx] = w_ih[j * C + c];
    } else if (idx < C * 512 + HID * 512) {    // w_hh_T[k][j] = w_hh[j][k]
        int t = idx - C * 512;
        int k = t >> 9, j = t & 511;
        w_hh_T[t] = w_hh[j * HID + k];
    } else if (idx < C * 512 + HID * 512 + 512) {
        int j = idx - (C * 512 + HID * 512);
        biassum[j] = b_ih[j] + b_hh[j];
    }
}

// ---------------- build: bucket events by (b, rf) ----------------
// Guideline 12: per-block LDS aggregation of chain registration, ONE global
// atomicAdd(&cnt[b]) per block (b uniform per block: 8 blocks per batch).
// R0->R1: per-thread same-address atomicAdd(&cnt[b]) serialized ~1810 deep
// and cost 177 us alone.
__global__ __launch_bounds__(256) void k_build(
    const int* __restrict__ coords, int* __restrict__ cntrf,
    int* __restrict__ map, int* __restrict__ cnt,
    int* __restrict__ chainrf, int* __restrict__ slots) {
    int idx = blockIdx.x * blockDim.x + threadIdx.x;   // grid exactly B*N
    int b = idx >> 11;              // /N ; uniform within block (256 | 2048)
    int n = idx & (N - 1);
    int x = coords[idx * 2 + 0];
    int y = coords[idx * 2 + 1];
    int rf = y * 128 + x;
    int pos = atomicAdd(&cntrf[b * NRF + rf], 1);
    if (pos < MAXLEN) slots[(b * NRF + rf) * MAXLEN + pos] = n;

    __shared__ int lcnt, lbase;
    if (threadIdx.x == 0) lcnt = 0;
    __syncthreads();
    int r = -1;
    if (pos == 0) r = atomicAdd(&lcnt, 1);     // LDS atomic: fast
    __syncthreads();
    if (threadIdx.x == 0) lbase = atomicAdd(&cnt[b], lcnt);  // 1 per block
    __syncthreads();
    if (pos == 0) {
        int k = lbase + r;
        chainrf[b * MAXCH + k] = rf;
        map[b * NRF + rf] = k;
    }
}

// ---------------- lstm over chains: one wave per chain ----------------
__global__ __launch_bounds__(64) void k_lstm(
    const float* __restrict__ features, const float* __restrict__ w_ih_T,
    const float* __restrict__ w_hh_T, const float* __restrict__ biassum,
    const int* __restrict__ cnt, const int* __restrict__ chainrf,
    const int* __restrict__ cntrf, const int* __restrict__ slots,
    float* __restrict__ hfin) {
    int b = blockIdx.x >> 9;        // grid = B * 512 blocks
    int j0 = blockIdx.x & 511;
    int lane = threadIdx.x;
    __shared__ float lds_h[HID];
    __shared__ float lds_x[C];
    int nch = cnt[b];
    for (int j = j0; j < nch; j += 512) {
        int rf = chainrf[b * MAXCH + j];
        int len = cntrf[b * NRF + rf];
        if (len > MAXLEN) len = MAXLEN;
        int ev[MAXLEN];
#pragma unroll
        for (int t = 0; t < MAXLEN; t++) ev[t] = 0x7fffffff;
        for (int t = 0; t < len; t++) ev[t] = slots[(b * NRF + rf) * MAXLEN + t];
        // sort ascending (time order); bubble over fixed 8, branch-free
#pragma unroll
        for (int a = 0; a < MAXLEN; a++)
#pragma unroll
            for (int q = 0; q < MAXLEN - 1; q++) {
                int u = ev[q], v = ev[q + 1];
                ev[q] = min(u, v);
                ev[q + 1] = max(u, v);
            }
        float c0 = 0.f, c1 = 0.f, h0 = 0.f, h1 = 0.f;
        for (int t = 0; t < len; t++) {
            int n = ev[t];
            if (lane < C) lds_x[lane] = features[(b * N + n) * C + lane];
            __syncthreads();
            float acc[8];
#pragma unroll
            for (int r = 0; r < 8; r++) acc[r] = biassum[lane + 64 * r];
#pragma unroll
            for (int ci = 0; ci < C; ci++) {
                float xv = lds_x[ci];
#pragma unroll
                for (int r = 0; r < 8; r++)
                    acc[r] += w_ih_T[ci * 512 + lane + 64 * r] * xv;
            }
            if (t > 0) {
                for (int k = 0; k < HID; k++) {
                    float hv = lds_h[k];
#pragma unroll
                    for (int r = 0; r < 8; r++)
                        acc[r] += w_hh_T[k * 512 + lane + 64 * r] * hv;
                }
            }
            // gate order (torch): i,f,g,o ; lane owns hid=lane (r even) and hid=lane+64 (r odd)
            float i0 = 1.f / (1.f + expf(-acc[0]));
            float i1 = 1.f / (1.f + expf(-acc[1]));
            float f0 = 1.f / (1.f + expf(-acc[2]));
            float f1 = 1.f / (1.f + expf(-acc[3]));
            float g0 = tanhf(acc[4]);
            float g1 = tanhf(acc[5]);
            float o0 = 1.f / (1.f + expf(-acc[6]));
            float o1 = 1.f / (1.f + expf(-acc[7]));
            c0 = f0 * c0 + i0 * g0;
            c1 = f1 * c1 + i1 * g1;
            h0 = o0 * tanhf(c0);
            h1 = o1 * tanhf(c1);
            __syncthreads();
            lds_h[lane] = h0;
            lds_h[lane + 64] = h1;
            __syncthreads();
        }
        hfin[(b * MAXCH + j) * HID + lane] = h0;
        hfin[(b * MAXCH + j) * HID + lane + 64] = h1;
    }
}

// ---------------- scatter to dense [B, HID, 128, 128] ----------------
__global__ __launch_bounds__(256) void k_scatter(
    const float* __restrict__ hfin, const int* __restrict__ map,
    float* __restrict__ out) {
    int b = blockIdx.x >> 7;        // grid = B*128
    int y = blockIdx.x & 127;
    int t = threadIdx.x;
    int xq = t & 31;                // x quad: covers x = 4*xq .. 4*xq+3
    int hg = t >> 5;                // hid group 0..7 (16 hids each)
    const int4* mrow = (const int4*)(map + b * NRF + y * 128);
    int4 kk = mrow[xq];
    const float* hb = hfin + (size_t)b * MAXCH * HID;
#pragma unroll
    for (int hh = 0; hh < 16; hh++) {
        int hid = hg * 16 + hh;
        float4 v;
        v.x = (kk.x < 0) ? 0.f : hb[kk.x * HID + hid];
        v.y = (kk.y < 0) ? 0.f : hb[kk.y * HID + hid];
        v.z = (kk.z < 0) ? 0.f : hb[kk.z * HID + hid];
        v.w = (kk.w < 0) ? 0.f : hb[kk.w * HID + hid];
        *(float4*)(out + ((((size_t)b * HID + hid) * 128 + y) * 128) + xq * 4) = v;
    }
}

extern "C" void kernel_launch(void* const* d_in, const int* in_sizes, int n_in,
                              void* d_out, int out_size, void* d_ws, size_t ws_size,
                              hipStream_t stream) {
    const float* features = (const float*)d_in[0];   // [B,N,C] f32
    const int*   coords   = (const int*)d_in[1];     // [B,N,2] i32
    const float* w_ih     = (const float*)d_in[2];   // [512,16]
    const float* w_hh     = (const float*)d_in[3];   // [512,128]
    const float* b_ih     = (const float*)d_in[4];   // [512]
    const float* b_hh     = (const float*)d_in[5];   // [512]
    float* out = (float*)d_out;                      // [B,128,128,128]

    char* ws = (char*)d_ws;
    float* w_ih_T  = (float*)(ws + 0);               //  32768 B
    float* w_hh_T  = (float*)(ws + 32768);           // 262144 B
    float* biassum = (float*)(ws + 294912);          //   2048 B
    int*   cntrf   = (int*)(ws + 296960);            // 524288 B
    int*   map     = (int*)(ws + 821248);            // 524288 B
    int*   cnt     = (int*)(ws + 1345536);           //     64 B
    int*   chainrf = (int*)(ws + 1345600);           //  65536 B
    int*   slots   = (int*)(ws + 1411136);           // 4194304 B
    float* hfin    = (float*)(ws + 5605440);         // 8388608 B -> ~13.4 MB total

    k_init<<<dim3((B * NRF + 255) / 256), dim3(256), 0, stream>>>(cntrf, map, cnt);
    k_prep<<<dim3((C * 512 + HID * 512 + 512 + 255) / 256), dim3(256), 0, stream>>>(
        w_ih, w_hh, b_ih, b_hh, w_ih_T, w_hh_T, biassum);
    k_build<<<dim3(B * N / 256), dim3(256), 0, stream>>>(
        coords, cntrf, map, cnt, chainrf, slots);
    k_lstm<<<dim3(B * 512), dim3(64), 0, stream>>>(
        features, w_ih_T, w_hh_T, biassum, cnt, chainrf, cntrf, slots, hfin);
    k_scatter<<<dim3(B * 128), dim3(256), 0, stream>>>(hfin, map, out);
}

// Round 3
// 158.008 us; speedup vs baseline: 2.4714x; 1.3598x over previous
//
#include <hip/hip_runtime.h>
#include <hip/hip_bf16.h>
#include <math.h>

#define B 8
#define N 2048
#define C 16
#define HID 128
#define NRF 16384      // 128*128
#define MAXLEN 8
#define MAXCH 2048     // max chains per batch (<= N)

// ---------------- init: zero per-rf counters, map=-1, cnt=0 ----------------
__global__ void k_init(int* __restrict__ cntrf, int* __restrict__ map,
                       int* __restrict__ cnt) {
    int i = blockIdx.x * blockDim.x + threadIdx.x;   // 0 .. B*NRF
    if (i < B * NRF) { cntrf[i] = 0; map[i] = -1; }
    if (i < B) cnt[i] = 0;
}

// ---------------- prep: transpose weights, sum biases ----------------
__global__ void k_prep(const float* __restrict__ w_ih, const float* __restrict__ w_hh,
                       const float* __restrict__ b_ih, const float* __restrict__ b_hh,
                       float* __restrict__ w_ih_T, float* __restrict__ w_hh_T,
                       float* __restrict__ biassum) {
    int idx = blockIdx.x * blockDim.x + threadIdx.x;
    if (idx < C * 512) {                       // w_ih_T[c][j] = w_ih[j][c]
        int c = idx >> 9, j = idx & 511;
        w_ih_T[idx] = w_ih[j * C + c];
    } else if (idx < C * 512 + HID * 512) {    // w_hh_T[k][j] = w_hh[j][k]
        int t = idx - C * 512;
        int k = t >> 9, j = t & 511;
        w_hh_T[t] = w_hh[j * HID + k];
    } else if (idx < C * 512 + HID * 512 + 512) {
        int j = idx - (C * 512 + HID * 512);
        biassum[j] = b_ih[j] + b_hh[j];
    }
}

// ---------------- build: bucket events by (b, rf) ----------------
// R1: per-block LDS aggregation; ONE global atomicAdd(&cnt[b]) per block.
__global__ __launch_bounds__(256) void k_build(
    const int* __restrict__ coords, int* __restrict__ cntrf,
    int* __restrict__ map, int* __restrict__ cnt,
    int* __restrict__ chainrf, int* __restrict__ slots) {
    int idx = blockIdx.x * blockDim.x + threadIdx.x;   // grid exactly B*N
    int b = idx >> 11;              // /N ; uniform within block (256 | 2048)
    int n = idx & (N - 1);
    int x = coords[idx * 2 + 0];
    int y = coords[idx * 2 + 1];
    int rf = y * 128 + x;
    int pos = atomicAdd(&cntrf[b * NRF + rf], 1);
    if (pos < MAXLEN) slots[(b * NRF + rf) * MAXLEN + pos] = n;

    __shared__ int lcnt, lbase;
    if (threadIdx.x == 0) lcnt = 0;
    __syncthreads();
    int r = -1;
    if (pos == 0) r = atomicAdd(&lcnt, 1);     // LDS atomic: fast
    __syncthreads();
    if (threadIdx.x == 0) lbase = atomicAdd(&cnt[b], lcnt);  // 1 per block
    __syncthreads();
    if (pos == 0) {
        int k = lbase + r;
        chainrf[b * MAXCH + k] = rf;
        map[b * NRF + rf] = k;
    }
}

// ---------------- gates: gates_x[e][512] = x_e @ w_ih^T + bias, ALL events ----
// R2: hoists the input matvec out of the latency-bound chain kernel into a
// dense, LDS-cached, write-coalesced throughput kernel (~33.5 MB write).
__global__ __launch_bounds__(256) void k_gates(
    const float* __restrict__ features, const float* __restrict__ w_ih_T,
    const float* __restrict__ biassum, float* __restrict__ gates_x) {
    __shared__ float ls_w[C * 512];   // 32 KB
    __shared__ float ls_b[512];
    __shared__ float ls_x[64 * C];    // 64 events' features, 4 KB
    int tid = threadIdx.x;
    for (int i = tid; i < C * 512; i += 256) ls_w[i] = w_ih_T[i];
    if (tid < 256) { ls_b[tid] = biassum[tid]; ls_b[tid + 256] = biassum[tid + 256]; }
    int e0 = blockIdx.x * 64;         // grid = 256 blocks -> 16384 events
    for (int i = tid; i < 64 * C; i += 256) ls_x[i] = features[e0 * C + i];
    __syncthreads();
    float b0 = ls_b[tid], b1 = ls_b[tid + 256];
    for (int e = 0; e < 64; e++) {
        float a0 = b0, a1 = b1;
#pragma unroll
        for (int ci = 0; ci < C; ci++) {
            float xv = ls_x[e * C + ci];
            a0 += ls_w[ci * 512 + tid] * xv;
            a1 += ls_w[ci * 512 + tid + 256] * xv;
        }
        gates_x[(size_t)(e0 + e) * 512 + tid] = a0;
        gates_x[(size_t)(e0 + e) * 512 + tid + 256] = a1;
    }
}

// ---------------- lstm over chains: one wave per chain ----------------
// Step 0: just 8 coalesced loads of gates_x. Steps t>0 (~1000 total across
// the whole problem): add h @ w_hh^T from L2-resident w_hh_T.
__global__ __launch_bounds__(64) void k_lstm(
    const float* __restrict__ gates_x, const float* __restrict__ w_hh_T,
    const int* __restrict__ cnt, const int* __restrict__ chainrf,
    const int* __restrict__ cntrf, const int* __restrict__ slots,
    float* __restrict__ hfin) {
    int b = blockIdx.x >> 9;        // grid = B * 512 blocks
    int j0 = blockIdx.x & 511;
    int lane = threadIdx.x;
    __shared__ float lds_h[HID];
    int nch = cnt[b];
    for (int j = j0; j < nch; j += 512) {
        int rf = chainrf[b * MAXCH + j];
        int len = cntrf[b * NRF + rf];
        if (len > MAXLEN) len = MAXLEN;
        const int* sl = slots + (size_t)(b * NRF + rf) * MAXLEN;
        int ev[MAXLEN];
#pragma unroll
        for (int t = 0; t < MAXLEN; t++) {   // static indices only -> VGPRs
            int v = sl[t];
            ev[t] = (t < len) ? v : 0x7fffffff;
        }
        // sort ascending (time order); static unrolled bubble network
#pragma unroll
        for (int a = 0; a < MAXLEN; a++)
#pragma unroll
            for (int q = 0; q < MAXLEN - 1; q++) {
                int u = ev[q], v = ev[q + 1];
                ev[q] = min(u, v);
                ev[q + 1] = max(u, v);
            }
        float c0 = 0.f, c1 = 0.f, h0 = 0.f, h1 = 0.f;
#pragma unroll
        for (int t = 0; t < MAXLEN; t++) {
            if (t >= len) break;             // wave-uniform branch
            int n = ev[t];                   // static index per unrolled copy
            const float* gx = gates_x + (size_t)(b * N + n) * 512;
            float acc[8];
#pragma unroll
            for (int r = 0; r < 8; r++) acc[r] = gx[lane + 64 * r];
            if (t > 0) {
                for (int k = 0; k < HID; k += 2) {
                    float hv0 = lds_h[k];
                    float hv1 = lds_h[k + 1];
#pragma unroll
                    for (int r = 0; r < 8; r++)
                        acc[r] += w_hh_T[k * 512 + lane + 64 * r] * hv0;
#pragma unroll
                    for (int r = 0; r < 8; r++)
                        acc[r] += w_hh_T[(k + 1) * 512 + lane + 64 * r] * hv1;
                }
            }
            // gate order (torch): i,f,g,o ; lane owns hid=lane and hid=lane+64
            float i0 = 1.f / (1.f + expf(-acc[0]));
            float i1 = 1.f / (1.f + expf(-acc[1]));
            float f0 = 1.f / (1.f + expf(-acc[2]));
            float f1 = 1.f / (1.f + expf(-acc[3]));
            float g0 = tanhf(acc[4]);
            float g1 = tanhf(acc[5]);
            float o0 = 1.f / (1.f + expf(-acc[6]));
            float o1 = 1.f / (1.f + expf(-acc[7]));
            c0 = f0 * c0 + i0 * g0;
            c1 = f1 * c1 + i1 * g1;
            h0 = o0 * tanhf(c0);
            h1 = o1 * tanhf(c1);
            if (t + 1 < len) {               // publish h for next step
                __syncthreads();
                lds_h[lane] = h0;
                lds_h[lane + 64] = h1;
                __syncthreads();
            }
        }
        hfin[(size_t)(b * MAXCH + j) * HID + lane] = h0;
        hfin[(size_t)(b * MAXCH + j) * HID + lane + 64] = h1;
    }
}

// ---------------- scatter to dense [B, HID, 128, 128] ----------------
__global__ __launch_bounds__(256) void k_scatter(
    const float* __restrict__ hfin, const int* __restrict__ map,
    float* __restrict__ out) {
    int b = blockIdx.x >> 7;        // grid = B*128
    int y = blockIdx.x & 127;
    int t = threadIdx.x;
    int xq = t & 31;                // x quad: covers x = 4*xq .. 4*xq+3
    int hg = t >> 5;                // hid group 0..7 (16 hids each)
    const int4* mrow = (const int4*)(map + b * NRF + y * 128);
    int4 kk = mrow[xq];
    const float* hb = hfin + (size_t)b * MAXCH * HID;
#pragma unroll
    for (int hh = 0; hh < 16; hh++) {
        int hid = hg * 16 + hh;
        float4 v;
        v.x = (kk.x < 0) ? 0.f : hb[kk.x * HID + hid];
        v.y = (kk.y < 0) ? 0.f : hb[kk.y * HID + hid];
        v.z = (kk.z < 0) ? 0.f : hb[kk.z * HID + hid];
        v.w = (kk.w < 0) ? 0.f : hb[kk.w * HID + hid];
        *(float4*)(out + ((((size_t)b * HID + hid) * 128 + y) * 128) + xq * 4) = v;
    }
}

extern "C" void kernel_launch(void* const* d_in, const int* in_sizes, int n_in,
                              void* d_out, int out_size, void* d_ws, size_t ws_size,
                              hipStream_t stream) {
    const float* features = (const float*)d_in[0];   // [B,N,C] f32
    const int*   coords   = (const int*)d_in[1];     // [B,N,2] i32
    const float* w_ih     = (const float*)d_in[2];   // [512,16]
    const float* w_hh     = (const float*)d_in[3];   // [512,128]
    const float* b_ih     = (const float*)d_in[4];   // [512]
    const float* b_hh     = (const float*)d_in[5];   // [512]
    float* out = (float*)d_out;                      // [B,128,128,128]

    char* ws = (char*)d_ws;
    float* w_ih_T  = (float*)(ws + 0);               //  32768 B
    float* w_hh_T  = (float*)(ws + 32768);           // 262144 B
    float* biassum = (float*)(ws + 294912);          //   2048 B
    int*   cntrf   = (int*)(ws + 296960);            // 524288 B
    int*   map     = (int*)(ws + 821248);            // 524288 B
    int*   cnt     = (int*)(ws + 1345536);           //     64 B
    int*   chainrf = (int*)(ws + 1345600);           //  65536 B
    int*   slots   = (int*)(ws + 1411136);           // 4194304 B
    float* hfin    = (float*)(ws + 5605440);         // 8388608 B
    float* gates_x = (float*)(ws + 13994048);        // 33554432 B -> ~47.5 MB total

    k_init<<<dim3((B * NRF + 255) / 256), dim3(256), 0, stream>>>(cntrf, map, cnt);
    k_prep<<<dim3((C * 512 + HID * 512 + 512 + 255) / 256), dim3(256), 0, stream>>>(
        w_ih, w_hh, b_ih, b_hh, w_ih_T, w_hh_T, biassum);
    k_build<<<dim3(B * N / 256), dim3(256), 0, stream>>>(
        coords, cntrf, map, cnt, chainrf, slots);
    k_gates<<<dim3(B * N / 64), dim3(256), 0, stream>>>(
        features, w_ih_T, biassum, gates_x);
    k_lstm<<<dim3(B * 512), dim3(64), 0, stream>>>(
        gates_x, w_hh_T, cnt, chainrf, cntrf, slots, hfin);
    k_scatter<<<dim3(B * 128), dim3(256), 0, stream>>>(hfin, map, out);
}

// Round 4
// 144.527 us; speedup vs baseline: 2.7020x; 1.0933x over previous
//
#include <hip/hip_runtime.h>
#include <hip/hip_bf16.h>
#include <math.h>

#define B 8
#define N 2048
#define C 16
#define HID 128
#define NRF 16384      // 128*128
#define MAXLEN 8
#define MAXCH 2048     // max chains per batch (<= N)

// ---------------- setup: init counters + transpose weights + bias ----------
// grid = 512 x 256 = 131072 = B*NRF threads exactly
__global__ __launch_bounds__(256) void k_setup(
    const float* __restrict__ w_ih, const float* __restrict__ w_hh,
    const float* __restrict__ b_ih, const float* __restrict__ b_hh,
    float* __restrict__ w_ih_T, float* __restrict__ w_hh_T,
    float* __restrict__ biassum, int* __restrict__ cntrf,
    int* __restrict__ map, int* __restrict__ cnt, int* __restrict__ mcnt) {
    int i = blockIdx.x * blockDim.x + threadIdx.x;
    cntrf[i] = 0;
    map[i] = -1;
    if (i < B) cnt[i] = 0;
    if (i == 0) mcnt[0] = 0;
    if (i < C * 512) {                 // w_ih_T[c][j] = w_ih[j][c]
        int c = i >> 9, j = i & 511;
        w_ih_T[i] = w_ih[j * C + c];
    }
    if (i < HID * 512) {               // w_hh_T[k][j] = w_hh[j][k]
        int k = i >> 9, j = i & 511;
        w_hh_T[i] = w_hh[j * HID + k];
    }
    if (i < 512) biassum[i] = b_ih[i] + b_hh[i];
}

// ---------------- build (blocks 0..63) + gates (all 256 blocks) ------------
// build: bucket events by (b, rf); block-aggregated chain registration
// (R0 lesson: contended same-address device atomics cost ~98 ns each).
// gates: gates_x[e][512] = x_e @ w_ih^T + bias for ALL events (R2 hoist).
__global__ __launch_bounds__(256) void k_buildgates(
    const int* __restrict__ coords, const float* __restrict__ features,
    const float* __restrict__ w_ih_T, const float* __restrict__ biassum,
    int* __restrict__ cntrf, int* __restrict__ map, int* __restrict__ cnt,
    int* __restrict__ chainrf, int* __restrict__ slots,
    float* __restrict__ gates_x) {
    int tid = threadIdx.x;
    __shared__ int lcnt, lbase;
    __shared__ float ls_w[C * 512];   // 32 KB
    __shared__ float ls_x[64 * C];    // 4 KB

    if (blockIdx.x < 64) {            // ---- build: 64*256 = B*N threads ----
        int idx = blockIdx.x * 256 + tid;
        int b = idx >> 11;            // uniform within block
        int n = idx & (N - 1);
        int x = coords[idx * 2 + 0];
        int y = coords[idx * 2 + 1];
        int rf = y * 128 + x;
        int pos = atomicAdd(&cntrf[b * NRF + rf], 1);
        if (pos < MAXLEN) slots[(b * NRF + rf) * MAXLEN + pos] = n;
        if (tid == 0) lcnt = 0;
        __syncthreads();
        int r = -1;
        if (pos == 0) r = atomicAdd(&lcnt, 1);
        __syncthreads();
        if (tid == 0) lbase = atomicAdd(&cnt[b], lcnt);   // 1 per block
        __syncthreads();
        if (pos == 0) {
            int k = lbase + r;
            chainrf[b * MAXCH + k] = rf;
            map[b * NRF + rf] = k;
        }
    }

    // ---- gates slice: 64 events per block ----
    for (int i = tid; i < C * 512; i += 256) ls_w[i] = w_ih_T[i];
    int e0 = blockIdx.x * 64;
    for (int i = tid; i < 64 * C; i += 256) ls_x[i] = features[e0 * C + i];
    float b0 = biassum[tid], b1 = biassum[tid + 256];
    __syncthreads();
    for (int e = 0; e < 64; e++) {
        float a0 = b0, a1 = b1;
#pragma unroll
        for (int ci = 0; ci < C; ci++) {
            float xv = ls_x[e * C + ci];
            a0 += ls_w[ci * 512 + tid] * xv;
            a1 += ls_w[ci * 512 + tid + 256] * xv;
        }
        gates_x[(size_t)(e0 + e) * 512 + tid] = a0;
        gates_x[(size_t)(e0 + e) * 512 + tid + 256] = a1;
    }
}

// ---------------- classify: build list of multi-event chains ---------------
// grid = 64 x 256 covering B*MAXCH chain slots; block-aggregated appends.
__global__ __launch_bounds__(256) void k_classify(
    const int* __restrict__ cnt, const int* __restrict__ chainrf,
    const int* __restrict__ cntrf, int* __restrict__ mcnt,
    int* __restrict__ mlist_brf, int* __restrict__ mlist_dst) {
    int tid = threadIdx.x;
    int idx = blockIdx.x * 256 + tid;      // 0 .. B*MAXCH-1
    int b = idx >> 11, j = idx & (MAXCH - 1);
    __shared__ int lcnt, lbase;
    __shared__ int lbrf[256], ldst[256];
    int len = 0, rf = 0;
    if (j < cnt[b]) {
        rf = chainrf[idx];
        len = cntrf[b * NRF + rf];
    }
    if (tid == 0) lcnt = 0;
    __syncthreads();
    if (len >= 2) {
        int r = atomicAdd(&lcnt, 1);
        lbrf[r] = b * NRF + rf;
        ldst[r] = idx;                     // = b*MAXCH + j
    }
    __syncthreads();
    if (tid == 0) lbase = atomicAdd(mcnt, lcnt);
    __syncthreads();
    for (int i = tid; i < lcnt; i += 256) {
        mlist_brf[lbase + i] = lbrf[i];
        mlist_dst[lbase + i] = ldst[i];
    }
}

// ---------------- singletons: no recurrence, pure throughput ---------------
// one wave per chain (grid-stride); f-gate never needed (c_prev = 0).
__global__ __launch_bounds__(256) void k_single(
    const float* __restrict__ gates_x, const int* __restrict__ cnt,
    const int* __restrict__ chainrf, const int* __restrict__ cntrf,
    const int* __restrict__ slots, float* __restrict__ hfin) {
    int lane = threadIdx.x & 63;
    int wid = blockIdx.x * 4 + (threadIdx.x >> 6);   // 8192 waves
    for (int ci = wid; ci < B * MAXCH; ci += 8192) {
        int b = ci >> 11, j = ci & (MAXCH - 1);
        if (j >= cnt[b]) continue;
        int rf = chainrf[ci];
        if (cntrf[b * NRF + rf] != 1) continue;
        int n = slots[(size_t)(b * NRF + rf) * MAXLEN];
        const float* gx = gates_x + (size_t)(b * N + n) * 512;
        float i0 = gx[lane],       i1 = gx[lane + 64];
        float g0 = gx[lane + 256], g1 = gx[lane + 320];
        float o0 = gx[lane + 384], o1 = gx[lane + 448];
        i0 = 1.f / (1.f + expf(-i0));
        i1 = 1.f / (1.f + expf(-i1));
        float c0 = i0 * tanhf(g0);
        float c1 = i1 * tanhf(g1);
        float h0 = (1.f / (1.f + expf(-o0))) * tanhf(c0);
        float h1 = (1.f / (1.f + expf(-o1))) * tanhf(c1);
        hfin[(size_t)ci * HID + lane] = h0;
        hfin[(size_t)ci * HID + lane + 64] = h1;
    }
}

// ---------------- multi-event chains: one 256-thread block per chain -------
// Per step each thread computes 2 gate cols (256 MACs, coalesced w_hh_T
// loads) vs R3's 8 cols/lane on one wave — 4x shorter critical path.
__global__ __launch_bounds__(256) void k_multi(
    const float* __restrict__ gates_x, const float* __restrict__ w_hh_T,
    const int* __restrict__ mcnt, const int* __restrict__ mlist_brf,
    const int* __restrict__ mlist_dst, const int* __restrict__ cntrf,
    const int* __restrict__ slots, float* __restrict__ hfin) {
    __shared__ float g512[512];
    __shared__ float hbuf[HID];
    int tid = threadIdx.x;
    int M = mcnt[0];
    for (int m = blockIdx.x; m < M; m += gridDim.x) {
        int brf = mlist_brf[m];
        int dst = mlist_dst[m];
        int b = brf >> 14;                 // NRF = 2^14
        int len = cntrf[brf];
        if (len > MAXLEN) len = MAXLEN;
        const int* sl = slots + (size_t)brf * MAXLEN;
        int ev[MAXLEN];
#pragma unroll
        for (int t = 0; t < MAXLEN; t++) {
            int v = sl[t];
            ev[t] = (t < len) ? v : 0x7fffffff;
        }
#pragma unroll
        for (int a = 0; a < MAXLEN; a++)   // sort ascending (time order)
#pragma unroll
            for (int q = 0; q < MAXLEN - 1; q++) {
                int u = ev[q], v = ev[q + 1];
                ev[q] = min(u, v);
                ev[q + 1] = max(u, v);
            }
        float c = 0.f;                     // state valid for tid < 128
        for (int t = 0; t < len; t++) {    // len is block-uniform
            const float* gx = gates_x + (size_t)(b * N + ev[t]) * 512;
            float a0 = gx[tid], a1 = gx[tid + 256];
            if (t > 0) {
#pragma unroll 8
                for (int k = 0; k < HID; k++) {
                    float hv = hbuf[k];
                    a0 += w_hh_T[k * 512 + tid] * hv;
                    a1 += w_hh_T[k * 512 + tid + 256] * hv;
                }
            }
            g512[tid] = a0;
            g512[tid + 256] = a1;
            __syncthreads();
            if (tid < HID) {
                float ig = 1.f / (1.f + expf(-g512[tid]));
                float fg = 1.f / (1.f + expf(-g512[tid + 128]));
                float gg = tanhf(g512[tid + 256]);
                float og = 1.f / (1.f + expf(-g512[tid + 384]));
                c = fg * c + ig * gg;
                hbuf[tid] = og * tanhf(c);
            }
            __syncthreads();
        }
        if (tid < HID) hfin[(size_t)dst * HID + tid] = hbuf[tid];
    }
}

// ---------------- scatter to dense [B, HID, 128, 128] ----------------
__global__ __launch_bounds__(256) void k_scatter(
    const float* __restrict__ hfin, const int* __restrict__ map,
    float* __restrict__ out) {
    int b = blockIdx.x >> 7;        // grid = B*128
    int y = blockIdx.x & 127;
    int t = threadIdx.x;
    int xq = t & 31;                // x quad: covers x = 4*xq .. 4*xq+3
    int hg = t >> 5;                // hid group 0..7 (16 hids each)
    const int4* mrow = (const int4*)(map + b * NRF + y * 128);
    int4 kk = mrow[xq];
    const float* hb = hfin + (size_t)b * MAXCH * HID;
#pragma unroll
    for (int hh = 0; hh < 16; hh++) {
        int hid = hg * 16 + hh;
        float4 v;
        v.x = (kk.x < 0) ? 0.f : hb[kk.x * HID + hid];
        v.y = (kk.y < 0) ? 0.f : hb[kk.y * HID + hid];
        v.z = (kk.z < 0) ? 0.f : hb[kk.z * HID + hid];
        v.w = (kk.w < 0) ? 0.f : hb[kk.w * HID + hid];
        *(float4*)(out + ((((size_t)b * HID + hid) * 128 + y) * 128) + xq * 4) = v;
    }
}

extern "C" void kernel_launch(void* const* d_in, const int* in_sizes, int n_in,
                              void* d_out, int out_size, void* d_ws, size_t ws_size,
                              hipStream_t stream) {
    const float* features = (const float*)d_in[0];   // [B,N,C] f32
    const int*   coords   = (const int*)d_in[1];     // [B,N,2] i32
    const float* w_ih     = (const float*)d_in[2];   // [512,16]
    const float* w_hh     = (const float*)d_in[3];   // [512,128]
    const float* b_ih     = (const float*)d_in[4];   // [512]
    const float* b_hh     = (const float*)d_in[5];   // [512]
    float* out = (float*)d_out;                      // [B,128,128,128]

    char* ws = (char*)d_ws;
    float* w_ih_T    = (float*)(ws + 0);             //    32768 B
    float* w_hh_T    = (float*)(ws + 32768);         //   262144 B
    float* biassum   = (float*)(ws + 294912);        //     2048 B
    int*   cntrf     = (int*)(ws + 296960);          //   524288 B
    int*   map       = (int*)(ws + 821248);          //   524288 B
    int*   cnt       = (int*)(ws + 1345536);         //       64 B
    int*   chainrf   = (int*)(ws + 1345600);         //    65536 B
    int*   slots     = (int*)(ws + 1411136);         //  4194304 B
    float* hfin      = (float*)(ws + 5605440);       //  8388608 B
    float* gates_x   = (float*)(ws + 13994048);      // 33554432 B
    int*   mcnt      = (int*)(ws + 47548480);        //       64 B
    int*   mlist_brf = (int*)(ws + 47548544);        //    65536 B
    int*   mlist_dst = (int*)(ws + 47614080);        //    65536 B -> ~45.5 MB

    k_setup<<<dim3(B * NRF / 256), dim3(256), 0, stream>>>(
        w_ih, w_hh, b_ih, b_hh, w_ih_T, w_hh_T, biassum, cntrf, map, cnt, mcnt);
    k_buildgates<<<dim3(B * N / 64), dim3(256), 0, stream>>>(
        coords, features, w_ih_T, biassum, cntrf, map, cnt, chainrf, slots, gates_x);
    k_classify<<<dim3(B * MAXCH / 256), dim3(256), 0, stream>>>(
        cnt, chainrf, cntrf, mcnt, mlist_brf, mlist_dst);
    k_single<<<dim3(2048), dim3(256), 0, stream>>>(
        gates_x, cnt, chainrf, cntrf, slots, hfin);
    k_multi<<<dim3(1024), dim3(256), 0, stream>>>(
        gates_x, w_hh_T, mcnt, mlist_brf, mlist_dst, cntrf, slots, hfin);
    k_scatter<<<dim3(B * 128), dim3(256), 0, stream>>>(hfin, map, out);
}